// Round 1
// baseline (485.796 us; speedup 1.0000x reference)
//
#include <hip/hip_runtime.h>
#include <math.h>

#define SEQ   4096
#define DIM   128
#define UDIM  64
#define BATCH 4
#define TQ    32
#define TK    64

#define KT_PAD 68   // KT[u][j]  : 16B-aligned float4 reads, 2-way banks
#define QT_PAD 36   // QT[u][qi] : 8B-aligned float2 reads
#define P_PAD  67   // Ps[qi][j] : ~2-way banks on scalar writes/reads

// ---------------- Kernel A: q,k,v = x @ W + b ----------------
// grid (B*S/4, 3), block 256. blockIdx.y selects projection so the
// 32KB W matrix stays L1-resident per CU.
__global__ __launch_bounds__(256) void qkv_proj(
    const float* __restrict__ x,
    const float* __restrict__ Wq, const float* __restrict__ bq,
    const float* __restrict__ Wk, const float* __restrict__ bk,
    const float* __restrict__ Wv, const float* __restrict__ bv,
    float* __restrict__ qkv)   // [3][B*S][U]
{
    const int proj = blockIdx.y;
    const float* __restrict__ Wp = (proj == 0) ? Wq : ((proj == 1) ? Wk : Wv);
    const float* __restrict__ bp = (proj == 0) ? bq : ((proj == 1) ? bk : bv);
    float* __restrict__ outp = qkv + (size_t)proj * (BATCH * SEQ * UDIM);

    const int tid = threadIdx.x;
    const int r0  = blockIdx.x * 4;

    __shared__ float xs[4][DIM];
    {
        const float2* xg = (const float2*)(x + (size_t)r0 * DIM);
        ((float2*)&xs[0][0])[tid] = xg[tid];   // 512 floats, coalesced
    }
    __syncthreads();

    const int w = tid >> 6;   // local row 0..3
    const int u = tid & 63;
    float acc = bp[u];
    #pragma unroll 8
    for (int d = 0; d < DIM; ++d)
        acc = fmaf(xs[w][d], Wp[d * UDIM + u], acc);
    outp[(size_t)(r0 + w) * UDIM + u] = acc;
}

// ---------------- Kernel B: flash attention, fp32 ----------------
// grid (S/TQ, B), block 256.
// Thread map: tq = tid>>4 owns q-rows {2tq, 2tq+1}; tk = tid&15 owns
// key cols {4tk..4tk+3} in the score phase and u cols {4tk..4tk+3} in PV.
// All softmax state for a row lives within one 16-lane group of one wave,
// so only the two staging barriers per key tile are needed.
__global__ __launch_bounds__(256) void flash_attn(
    const float* __restrict__ qkv, float* __restrict__ out)
{
    const int tile = blockIdx.x;
    const int b    = blockIdx.y;
    const int q0   = tile * TQ;

    const float* __restrict__ qg = qkv + (size_t)b * SEQ * UDIM;
    const float* __restrict__ kg = qkv + (size_t)(BATCH * SEQ * UDIM) + (size_t)b * SEQ * UDIM;
    const float* __restrict__ vg = qkv + (size_t)2 * (BATCH * SEQ * UDIM) + (size_t)b * SEQ * UDIM;

    __shared__ float QT[UDIM][QT_PAD];  // QT[u][qi]
    __shared__ float KT[UDIM][KT_PAD];  // KT[u][j]
    __shared__ float Vs[TK][UDIM];      // Vs[j][u]
    __shared__ float Ps[TQ][P_PAD];     // Ps[qi][j]
    __shared__ float m_s[TQ], l_s[TQ];

    const int tid = threadIdx.x;
    const int tq  = tid >> 4;   // 0..15
    const int tk  = tid & 15;   // 0..15

    // Q tile -> LDS, transposed (once per block)
    for (int e = tid; e < TQ * UDIM; e += 256) {
        int qi = e >> 6, u = e & 63;
        QT[u][qi] = qg[(size_t)(q0 + qi) * UDIM + u];
    }
    if (tid < TQ) { m_s[tid] = -INFINITY; l_s[tid] = 0.f; }

    float o0[4] = {0.f, 0.f, 0.f, 0.f};
    float o1[4] = {0.f, 0.f, 0.f, 0.f};

    for (int kt = 0; kt < SEQ / TK; ++kt) {
        __syncthreads();   // protect LDS tiles from previous iteration's readers
        // ---- stage K (transposed) and V (flat) ----
        {
            const float4* ksrc = (const float4*)(kg + (size_t)kt * TK * UDIM);
            const float4* vsrc = (const float4*)(vg + (size_t)kt * TK * UDIM);
            #pragma unroll
            for (int i = 0; i < 4; ++i) {
                int e4 = i * 256 + tid;          // float4 index 0..1023
                float4 kv = ksrc[e4];
                int e = e4 * 4;
                int j = e >> 6, u = e & 63;      // u in {0,4,...,60}
                KT[u + 0][j] = kv.x;
                KT[u + 1][j] = kv.y;
                KT[u + 2][j] = kv.z;
                KT[u + 3][j] = kv.w;
                ((float4*)&Vs[0][0])[e4] = vsrc[e4];
            }
        }
        __syncthreads();

        // ---- scores: S[2][4] over 64-long dot products ----
        float s0[4] = {0.f, 0.f, 0.f, 0.f};
        float s1[4] = {0.f, 0.f, 0.f, 0.f};
        #pragma unroll 8
        for (int u = 0; u < UDIM; ++u) {
            float4 kv = *(const float4*)&KT[u][4 * tk];
            float2 qv = *(const float2*)&QT[u][2 * tq];
            s0[0] = fmaf(qv.x, kv.x, s0[0]);
            s0[1] = fmaf(qv.x, kv.y, s0[1]);
            s0[2] = fmaf(qv.x, kv.z, s0[2]);
            s0[3] = fmaf(qv.x, kv.w, s0[3]);
            s1[0] = fmaf(qv.y, kv.x, s1[0]);
            s1[1] = fmaf(qv.y, kv.y, s1[1]);
            s1[2] = fmaf(qv.y, kv.z, s1[2]);
            s1[3] = fmaf(qv.y, kv.w, s1[3]);
        }

        // ---- online softmax (within 16-lane group) ----
        float rm0 = fmaxf(fmaxf(s0[0], s0[1]), fmaxf(s0[2], s0[3]));
        float rm1 = fmaxf(fmaxf(s1[0], s1[1]), fmaxf(s1[2], s1[3]));
        #pragma unroll
        for (int mask = 1; mask < 16; mask <<= 1) {
            rm0 = fmaxf(rm0, __shfl_xor(rm0, mask));
            rm1 = fmaxf(rm1, __shfl_xor(rm1, mask));
        }
        float m_old0 = m_s[2 * tq], m_old1 = m_s[2 * tq + 1];
        float m_new0 = fmaxf(m_old0, rm0), m_new1 = fmaxf(m_old1, rm1);
        float al0 = __expf(m_old0 - m_new0);   // exp(-inf)=0 on first tile
        float al1 = __expf(m_old1 - m_new1);

        float p0[4], p1[4];
        float rs0 = 0.f, rs1 = 0.f;
        #pragma unroll
        for (int c = 0; c < 4; ++c) {
            p0[c] = __expf(s0[c] - m_new0); rs0 += p0[c];
            p1[c] = __expf(s1[c] - m_new1); rs1 += p1[c];
        }
        #pragma unroll
        for (int mask = 1; mask < 16; mask <<= 1) {
            rs0 += __shfl_xor(rs0, mask);
            rs1 += __shfl_xor(rs1, mask);
        }
        if (tk == 0) {
            m_s[2 * tq]     = m_new0;
            m_s[2 * tq + 1] = m_new1;
            l_s[2 * tq]     = l_s[2 * tq]     * al0 + rs0;
            l_s[2 * tq + 1] = l_s[2 * tq + 1] * al1 + rs1;
        }

        // ---- P -> LDS (read back by same wave; DS ops in-order per wave) ----
        #pragma unroll
        for (int c = 0; c < 4; ++c) {
            Ps[2 * tq][4 * tk + c]     = p0[c];
            Ps[2 * tq + 1][4 * tk + c] = p1[c];
        }

        // ---- rescale O, accumulate P @ V ----
        #pragma unroll
        for (int c = 0; c < 4; ++c) { o0[c] *= al0; o1[c] *= al1; }

        const float* __restrict__ pr0 = &Ps[2 * tq][0];
        const float* __restrict__ pr1 = &Ps[2 * tq + 1][0];
        #pragma unroll 8
        for (int j = 0; j < TK; ++j) {
            float4 vv = *(const float4*)&Vs[j][4 * tk];
            float pa = pr0[j], pb = pr1[j];
            o0[0] = fmaf(pa, vv.x, o0[0]);
            o0[1] = fmaf(pa, vv.y, o0[1]);
            o0[2] = fmaf(pa, vv.z, o0[2]);
            o0[3] = fmaf(pa, vv.w, o0[3]);
            o1[0] = fmaf(pb, vv.x, o1[0]);
            o1[1] = fmaf(pb, vv.y, o1[1]);
            o1[2] = fmaf(pb, vv.z, o1[2]);
            o1[3] = fmaf(pb, vv.w, o1[3]);
        }
    }

    // ---- epilogue: normalize and store (float4, coalesced) ----
    float linv0 = 1.f / l_s[2 * tq];
    float linv1 = 1.f / l_s[2 * tq + 1];
    float* __restrict__ orow0 = out + ((size_t)b * SEQ + q0 + 2 * tq) * UDIM + 4 * tk;
    float* __restrict__ orow1 = orow0 + UDIM;
    *(float4*)orow0 = make_float4(o0[0] * linv0, o0[1] * linv0, o0[2] * linv0, o0[3] * linv0);
    *(float4*)orow1 = make_float4(o1[0] * linv1, o1[1] * linv1, o1[2] * linv1, o1[3] * linv1);
}

extern "C" void kernel_launch(void* const* d_in, const int* in_sizes, int n_in,
                              void* d_out, int out_size, void* d_ws, size_t ws_size,
                              hipStream_t stream) {
    (void)in_sizes; (void)n_in; (void)out_size; (void)ws_size;
    const float* x  = (const float*)d_in[0];
    const float* Wq = (const float*)d_in[1];
    const float* bq = (const float*)d_in[2];
    const float* Wk = (const float*)d_in[3];
    const float* bk = (const float*)d_in[4];
    const float* Wv = (const float*)d_in[5];
    const float* bv = (const float*)d_in[6];
    float* outp = (float*)d_out;
    float* qkv  = (float*)d_ws;   // [3][B*S][U] = 12 MB

    dim3 gA(BATCH * SEQ / 4, 3);
    qkv_proj<<<gA, 256, 0, stream>>>(x, Wq, bq, Wk, bk, Wv, bv, qkv);

    dim3 gB(SEQ / TQ, BATCH);
    flash_attn<<<gB, 256, 0, stream>>>(qkv, outp);
}

// Round 3
// 145.685 us; speedup vs baseline: 3.3346x; 3.3346x over previous
//
#include <hip/hip_runtime.h>
#include <hip/hip_fp16.h>
#include <math.h>

#define SEQ   4096
#define DIM   128
#define UDIM  64
#define BATCH 4
#define BS    (BATCH*SEQ)

typedef _Float16 h8 __attribute__((ext_vector_type(8)));
typedef _Float16 h2 __attribute__((ext_vector_type(2)));
typedef float    f4 __attribute__((ext_vector_type(4)));

#define MFMA16(a,b,c) __builtin_amdgcn_mfma_f32_16x16x32_f16((a),(b),(c),0,0,0)

// cvt_pkrtz returns __fp16x2; bit_cast to our h2 (same 4-byte layout)
__device__ __forceinline__ h2 pk2(float a, float b) {
  return __builtin_bit_cast(h2, __builtin_amdgcn_cvt_pkrtz(a, b));
}

// LDS strides: 144B = 36 words; 36 = 4*9, 9 odd -> each consecutive 8-lane
// phase of a b128 access covers all 32 banks exactly once (conflict-free),
// and 144 % 16 == 0 keeps ds_read_b128 16B-aligned.
#define PS_STRIDE 144
#define VT_STRIDE 144
#define L2E 1.44269504088896f

// butterfly max over 16-lane groups on packed f16x2 (4 DS swizzles per value)
__device__ __forceinline__ h2 pkmax_bcast16(h2 v) {
  h2 o;
  o = __builtin_bit_cast(h2, __builtin_amdgcn_ds_swizzle(__builtin_bit_cast(int, v), 0x041F));
  v = __builtin_elementwise_max(v, o);
  o = __builtin_bit_cast(h2, __builtin_amdgcn_ds_swizzle(__builtin_bit_cast(int, v), 0x081F));
  v = __builtin_elementwise_max(v, o);
  o = __builtin_bit_cast(h2, __builtin_amdgcn_ds_swizzle(__builtin_bit_cast(int, v), 0x101F));
  v = __builtin_elementwise_max(v, o);
  o = __builtin_bit_cast(h2, __builtin_amdgcn_ds_swizzle(__builtin_bit_cast(int, v), 0x201F));
  v = __builtin_elementwise_max(v, o);
  return v;
}

// ---------------- Kernel A: qkv projection via MFMA ----------------
// grid (BS/128, 3), block 256 (4 waves x 32 rows). W B-frags live in regs;
// x A-frags read direct from global (fp32 -> f16). q,k stored [s][u] f16
// (pair-packed b32 global stores); v stored transposed [u][s] f16 via LDS bounce.
__global__ __launch_bounds__(256, 2) void proj_mfma(
    const float* __restrict__ x,
    const float* __restrict__ Wq, const float* __restrict__ bq,
    const float* __restrict__ Wk, const float* __restrict__ bk,
    const float* __restrict__ Wv, const float* __restrict__ bv,
    _Float16* __restrict__ qf, _Float16* __restrict__ kf, _Float16* __restrict__ vt)
{
  const int proj = blockIdx.y;
  const float* __restrict__ W    = proj==0 ? Wq : (proj==1 ? Wk : Wv);
  const float* __restrict__ bias = proj==0 ? bq : (proj==1 ? bk : bv);
  const int tid  = threadIdx.x;
  const int lane = tid & 63, wv = tid >> 6;
  const int n = lane & 15, quad = lane >> 4;
  const int r0 = blockIdx.x * 128;

  __shared__ __align__(16) char sbuf[UDIM * 304];  // v^T bounce (stride 304B, 16-aligned)

  // W B-fragments: B[k=quad*8+j][n], k=d, n=u
  h8 wf[4][4];
  #pragma unroll
  for (int ks = 0; ks < 4; ++ks)
    #pragma unroll
    for (int nt = 0; nt < 4; ++nt)
      #pragma unroll
      for (int j = 0; j < 8; ++j)
        wf[ks][nt][j] = (_Float16)W[(ks*32 + quad*8 + j)*UDIM + nt*16 + n];

  // x A-fragments: A[m=lane&15][k=quad*8+j], m=row, k=d
  h8 xa[2][4];
  #pragma unroll
  for (int mt = 0; mt < 2; ++mt)
    #pragma unroll
    for (int ks = 0; ks < 4; ++ks) {
      const float* xp = x + (size_t)(r0 + wv*32 + mt*16 + n)*DIM + ks*32 + quad*8;
      const f4 a = *(const f4*)xp, b = *(const f4*)(xp + 4);
      h8 v;
      v[0]=(_Float16)a[0]; v[1]=(_Float16)a[1]; v[2]=(_Float16)a[2]; v[3]=(_Float16)a[3];
      v[4]=(_Float16)b[0]; v[5]=(_Float16)b[1]; v[6]=(_Float16)b[2]; v[7]=(_Float16)b[3];
      xa[mt][ks] = v;
    }

  f4 acc[2][4];
  #pragma unroll
  for (int mt = 0; mt < 2; ++mt)
    #pragma unroll
    for (int nt = 0; nt < 4; ++nt)
      acc[mt][nt] = (f4){0.f, 0.f, 0.f, 0.f};

  #pragma unroll
  for (int ks = 0; ks < 4; ++ks)
    #pragma unroll
    for (int mt = 0; mt < 2; ++mt)
      #pragma unroll
      for (int nt = 0; nt < 4; ++nt)
        acc[mt][nt] = MFMA16(xa[mt][ks], wf[ks][nt], acc[mt][nt]);

  float bb[4];
  #pragma unroll
  for (int nt = 0; nt < 4; ++nt) bb[nt] = bias[nt*16 + n];
  #pragma unroll
  for (int mt = 0; mt < 2; ++mt)
    #pragma unroll
    for (int nt = 0; nt < 4; ++nt)
      #pragma unroll
      for (int r = 0; r < 4; ++r)
        acc[mt][nt][r] += bb[nt];

  if (proj < 2) {
    // q,k -> [s][u] f16. C-frag has rows quad*4+reg at col n; DPP-swap lane
    // pairs + v_perm assemble (row, col-pair) b32 words -> coalesced-ish stores.
    _Float16* __restrict__ out = (proj == 0) ? qf : kf;
    const int par = lane & 1;
    const unsigned sel = par ? 0x03020706u : 0x05040100u;
    #pragma unroll
    for (int mt = 0; mt < 2; ++mt)
      #pragma unroll
      for (int nt = 0; nt < 4; ++nt)
        #pragma unroll
        for (int p = 0; p < 2; ++p) {
          const int r = 2*p;
          h2 pkv = pk2(acc[mt][nt][r], acc[mt][nt][r+1]);
          unsigned A  = __builtin_bit_cast(unsigned, pkv);
          unsigned Bs = (unsigned)__builtin_amdgcn_mov_dpp((int)A, 0xB1, 0xF, 0xF, true);
          unsigned w  = __builtin_amdgcn_perm(Bs, A, sel);
          const int row = r0 + wv*32 + mt*16 + 4*quad + r + par;
          const int col = nt*16 + n - par;   // even
          *(unsigned*)((char*)out + ((size_t)row*UDIM + col)*2) = w;
        }
  } else {
    // v -> v^T [u][s] f16 via LDS bounce. C-frag reg pairs are consecutive
    // rows at fixed col u -> pack to b32 directly (no DPP needed).
    #pragma unroll
    for (int mt = 0; mt < 2; ++mt)
      #pragma unroll
      for (int nt = 0; nt < 4; ++nt)
        #pragma unroll
        for (int p = 0; p < 2; ++p) {
          const int r = 2*p;
          h2 pkv = pk2(acc[mt][nt][r], acc[mt][nt][r+1]);
          const int u = nt*16 + n;
          const int lrow = wv*32 + mt*16 + 4*quad + r;
          *(unsigned*)(sbuf + u*304 + lrow*2) = __builtin_bit_cast(unsigned, pkv);
        }
    __syncthreads();
    const int b  = r0 / SEQ;
    const int s0 = r0 % SEQ;
    #pragma unroll
    for (int i = 0; i < 4; ++i) {
      const int e = tid + 256*i;
      const int u = e >> 4, ch = e & 15;
      h8 v = *(const h8*)(sbuf + u*304 + ch*16);
      *(h8*)(vt + ((size_t)b*UDIM + u)*SEQ + s0 + ch*8) = v;
    }
  }
}

// ---------------- Kernel B: flash attention, f16 MFMA ----------------
// grid (SEQ/128, BATCH, nsplit), block 256. Wave owns 32 q-rows (2 M-tiles).
// K B-frags direct from global (contiguous 2KB per frag, L1-served);
// V^T staged in LDS; P LDS round-trip C->A layout; l carried as a 5th
// accumulator column via a constant "ones" B-fragment (no sum reduction).
__global__ __launch_bounds__(256, 2) void flash_attn_f16(
    const _Float16* __restrict__ qf, const _Float16* __restrict__ kf,
    const _Float16* __restrict__ vt,
    float* __restrict__ opart, float* __restrict__ Mp, float* __restrict__ Lp,
    int nkt)
{
  const int qt = blockIdx.x, b = blockIdx.y, sp = blockIdx.z;
  const _Float16* __restrict__ qb = qf + (size_t)b*SEQ*UDIM;
  const _Float16* __restrict__ kb = kf + (size_t)b*SEQ*UDIM;
  const _Float16* __restrict__ vb = vt + (size_t)b*UDIM*SEQ;

  __shared__ __align__(16) char VTs[UDIM * VT_STRIDE];
  __shared__ __align__(16) char Ps [128  * PS_STRIDE];

  const int tid = threadIdx.x;
  const int lane = tid & 63, wv = tid >> 6;
  const int n = lane & 15, quad = lane >> 4;
  const int wrow0 = wv * 32;
  const int qrow0 = qt * 128;

  // Q A-frags in registers for the whole block
  h8 qa[2][2];
  #pragma unroll
  for (int mt = 0; mt < 2; ++mt)
    #pragma unroll
    for (int ks = 0; ks < 2; ++ks)
      qa[mt][ks] = *(const h8*)(qb + (size_t)(qrow0 + wrow0 + mt*16 + n)*UDIM + ks*32 + quad*8);

  f4 O[2][5];
  #pragma unroll
  for (int mt = 0; mt < 2; ++mt)
    #pragma unroll
    for (int c = 0; c < 5; ++c)
      O[mt][c] = (f4){0.f, 0.f, 0.f, 0.f};

  float M[2][4];
  #pragma unroll
  for (int mt = 0; mt < 2; ++mt)
    #pragma unroll
    for (int r = 0; r < 4; ++r) M[mt][r] = -1e30f;

  h8 ones;
  { const _Float16 o = (n == 0) ? (_Float16)1.0f : (_Float16)0.0f;
    #pragma unroll
    for (int j = 0; j < 8; ++j) ones[j] = o; }

  const int par = lane & 1;
  const unsigned psel = par ? 0x03020706u : 0x05040100u;

  const int kt0 = sp * nkt;
  for (int kt = kt0; kt < kt0 + nkt; ++kt) {
    __syncthreads();   // protect VTs from previous iteration's readers
    #pragma unroll
    for (int i = 0; i < 2; ++i) {
      const int e = tid + 256*i, u = e >> 3, kc = e & 7;
      *(h8*)(VTs + u*VT_STRIDE + kc*16) =
          *(const h8*)(vb + (size_t)u*SEQ + kt*64 + kc*8);
    }
    __syncthreads();

    // ---- QK^T: K B-frags straight from global ----
    f4 S[2][4];
    #pragma unroll
    for (int mt = 0; mt < 2; ++mt)
      #pragma unroll
      for (int nt = 0; nt < 4; ++nt)
        S[mt][nt] = (f4){0.f, 0.f, 0.f, 0.f};
    #pragma unroll
    for (int nt = 0; nt < 4; ++nt) {
      const _Float16* kp = kb + (size_t)(kt*64 + nt*16 + n)*UDIM + quad*8;
      const h8 k0 = *(const h8*)kp;
      const h8 k1 = *(const h8*)(kp + 32);
      #pragma unroll
      for (int mt = 0; mt < 2; ++mt) {
        S[mt][nt] = MFMA16(qa[mt][0], k0, S[mt][nt]);
        S[mt][nt] = MFMA16(qa[mt][1], k1, S[mt][nt]);
      }
    }

    // ---- online softmax: per-row max (packed butterfly), log2 domain ----
    float alpha[2][4];
    #pragma unroll
    for (int mt = 0; mt < 2; ++mt) {
      float rm[4];
      #pragma unroll
      for (int r = 0; r < 4; ++r)
        rm[r] = fmaxf(fmaxf(S[mt][0][r], S[mt][1][r]), fmaxf(S[mt][2][r], S[mt][3][r]));
      #pragma unroll
      for (int p = 0; p < 2; ++p) {
        h2 v = pk2(rm[2*p], rm[2*p+1]);
        v = pkmax_bcast16(v);
        #pragma unroll
        for (int t = 0; t < 2; ++t) {
          const int r = 2*p + t;
          const float rl = (float)v[t] * L2E;
          const float mo = M[mt][r];
          const float mn = fmaxf(mo, rl);
          alpha[mt][r] = exp2f(mo - mn);
          M[mt][r] = mn;
        }
      }
    }

    // ---- P = exp2(S*log2e - M); pack + write to Ps [row][key] f16 ----
    #pragma unroll
    for (int mt = 0; mt < 2; ++mt)
      #pragma unroll
      for (int nt = 0; nt < 4; ++nt) {
        #pragma unroll
        for (int r = 0; r < 4; ++r)
          S[mt][nt][r] = exp2f(fmaf(S[mt][nt][r], L2E, -M[mt][r]));
        #pragma unroll
        for (int p = 0; p < 2; ++p) {
          const int r = 2*p;
          h2 pkv = pk2(S[mt][nt][r], S[mt][nt][r+1]);
          unsigned A  = __builtin_bit_cast(unsigned, pkv);
          unsigned Bs = (unsigned)__builtin_amdgcn_mov_dpp((int)A, 0xB1, 0xF, 0xF, true);
          unsigned w  = __builtin_amdgcn_perm(Bs, A, psel);
          const int row = wrow0 + mt*16 + 4*quad + r + par;
          const int col = nt*16 + n - par;
          *(unsigned*)(Ps + row*PS_STRIDE + col*2) = w;
        }
      }

    // ---- rescale O (incl. l column) ----
    #pragma unroll
    for (int mt = 0; mt < 2; ++mt)
      #pragma unroll
      for (int c = 0; c < 5; ++c)
        #pragma unroll
        for (int r = 0; r < 4; ++r)
          O[mt][c][r] *= alpha[mt][r];

    // ---- PV (+ l via ones column); P read back by same wave (in-order DS) ----
    #pragma unroll
    for (int ks = 0; ks < 2; ++ks) {
      h8 pa[2];
      #pragma unroll
      for (int mt = 0; mt < 2; ++mt)
        pa[mt] = *(const h8*)(Ps + (wrow0 + mt*16 + n)*PS_STRIDE + ks*64 + quad*16);
      #pragma unroll
      for (int nt = 0; nt < 4; ++nt) {
        const h8 vf = *(const h8*)(VTs + (nt*16 + n)*VT_STRIDE + ks*64 + quad*16);
        #pragma unroll
        for (int mt = 0; mt < 2; ++mt)
          O[mt][nt] = MFMA16(pa[mt], vf, O[mt][nt]);
      }
      #pragma unroll
      for (int mt = 0; mt < 2; ++mt)
        O[mt][4] = MFMA16(pa[mt], ones, O[mt][4]);
    }
  }

  // ---- epilogue: un-normalized partial O, M (log2 domain), l ----
  const size_t rowbase = (size_t)sp*BS + (size_t)b*SEQ + qrow0;
  #pragma unroll
  for (int mt = 0; mt < 2; ++mt) {
    #pragma unroll
    for (int nt = 0; nt < 4; ++nt)
      #pragma unroll
      for (int r = 0; r < 4; ++r) {
        const int row = wrow0 + mt*16 + 4*quad + r;
        opart[(rowbase + row)*UDIM + nt*16 + n] = O[mt][nt][r];
      }
    if (n == 0) {
      #pragma unroll
      for (int r = 0; r < 4; ++r) {
        const int row = wrow0 + mt*16 + 4*quad + r;
        Mp[rowbase + row] = M[mt][r];
        Lp[rowbase + row] = O[mt][4][r];
      }
    }
  }
}

// ---------------- Kernel C: merge key-split partials ----------------
__global__ __launch_bounds__(256) void merge_out(
    const float* __restrict__ opart, const float* __restrict__ Mp,
    const float* __restrict__ Lp, float* __restrict__ out, int nsplit)
{
  const int tid = threadIdx.x;
  const int row = blockIdx.x*4 + (tid >> 6);
  const int u = tid & 63;
  float M = -1e30f;
  for (int s = 0; s < nsplit; ++s) M = fmaxf(M, Mp[(size_t)s*BS + row]);
  float num = 0.f, den = 0.f;
  for (int s = 0; s < nsplit; ++s) {
    const float w = exp2f(Mp[(size_t)s*BS + row] - M);
    den += w * Lp[(size_t)s*BS + row];
    num += w * opart[((size_t)s*BS + row)*UDIM + u];
  }
  out[(size_t)row*UDIM + u] = num / den;
}

extern "C" void kernel_launch(void* const* d_in, const int* in_sizes, int n_in,
                              void* d_out, int out_size, void* d_ws, size_t ws_size,
                              hipStream_t stream) {
  (void)in_sizes; (void)n_in; (void)out_size;
  const float* x  = (const float*)d_in[0];
  const float* Wq = (const float*)d_in[1];
  const float* bq = (const float*)d_in[2];
  const float* Wk = (const float*)d_in[3];
  const float* bk = (const float*)d_in[4];
  const float* Wv = (const float*)d_in[5];
  const float* bv = (const float*)d_in[6];
  float* out = (float*)d_out;

  char* ws = (char*)d_ws;
  const size_t fBytes = (size_t)BS * UDIM * 2;   // 2 MB per f16 tensor
  // ws budget: q,k,vT (6MB) + nsplit*(Mp+Lp 128KB + opart 4MB)
  auto need = [](int nsp) {
    return (size_t)3*BS*UDIM*2 + (size_t)nsp*BS*4*2 + (size_t)nsp*BS*UDIM*4;
  };
  int nsplit;
  if      (ws_size >= need(4)) nsplit = 4;
  else if (ws_size >= need(2)) nsplit = 2;
  else                         nsplit = 1;

  _Float16* qf = (_Float16*)(ws);
  _Float16* kf = (_Float16*)(ws + fBytes);
  _Float16* vt = (_Float16*)(ws + 2*fBytes);
  float* Mp    = (float*)(ws + 3*fBytes);
  float* Lp    = (float*)(ws + 3*fBytes + (size_t)nsplit*BS*4);
  float* opart = (float*)(ws + 3*fBytes + (size_t)nsplit*BS*8);

  proj_mfma<<<dim3(BS/128, 3), 256, 0, stream>>>(x, Wq, bq, Wk, bk, Wv, bv, qf, kf, vt);
  flash_attn_f16<<<dim3(SEQ/128, BATCH, nsplit), 256, 0, stream>>>(
      qf, kf, vt, opart, Mp, Lp, (SEQ/64)/nsplit);
  merge_out<<<dim3(BS/4), 256, 0, stream>>>(opart, Mp, Lp, out, nsplit);
}